// Round 1
// baseline (376.013 us; speedup 1.0000x reference)
//
#include <hip/hip_runtime.h>

typedef short bf16x8 __attribute__((ext_vector_type(8)));
typedef float f32x4 __attribute__((ext_vector_type(4)));

#define NBJ 16          // BS*J
#define NMT 125         // 2000/16 m-tiles
#define NKT 63          // ceil(2000/32) k-tiles
#define NCH 128         // J*C channels
#define NM  2000
#define NB  4
#define NJ  4
#define NC  32
#define BN_EPS 1e-5f

// ---- helpers: fp32 -> bf16 (RNE) hi, and residual lo ----
__device__ inline void bf16_split(float v, short& hi, short& lo) {
    unsigned u = __float_as_uint(v);
    unsigned rn = (u + 0x7fffu + ((u >> 16) & 1u)) & 0xffff0000u;
    hi = (short)(rn >> 16);
    float d = v - __uint_as_float(rn);
    unsigned ud = __float_as_uint(d);
    lo = (short)((ud + 0x7fffu + ((ud >> 16) & 1u)) >> 16);
}

// ---- kernel 1: build x fragments in MFMA B-operand layout; zero stats ----
// B-frag for 16x16x32: lane holds B[k = (lane>>4)*8 + j][n = lane&15], j=0..7
// storage: xfrag[((b*63 + kt)*2 + ct)*2 + hl][lane][8 shorts]
__global__ __launch_bounds__(256) void prep_kernel(
        const float* __restrict__ x, short* __restrict__ xfrag,
        float* __restrict__ csum /* csum[128] then csumsq[128] contiguous */) {
    int gid = blockIdx.x * 256 + threadIdx.x;     // 0..32255
    if (gid < 256) csum[gid] = 0.f;
    int lane = gid & 63;
    int t = gid >> 6;
    int ct = t & 1; t >>= 1;
    int kt = t % NKT;
    int b  = t / NKT;
    int c  = ct * 16 + (lane & 15);
    int k0 = kt * 32 + (lane >> 4) * 8;
    const float* xp = x + ((size_t)b * NC + c) * NM;
    bf16x8 hi, lo;
#pragma unroll
    for (int j = 0; j < 8; ++j) {
        int k = k0 + j;
        float v = (k < NM) ? xp[k] : 0.f;
        short h, l;
        bf16_split(v, h, l);
        hi[j] = h; lo[j] = l;
    }
    size_t base = ((((size_t)b * NKT + kt) * 2 + ct) * 2) * 512 + (size_t)lane * 8;
    *(bf16x8*)(xfrag + base)       = hi;
    *(bf16x8*)(xfrag + base + 512) = lo;
}

// ---- kernel 2: GEMM y[bj][m][c] = sum_n W[bj][m][n] * x[b][c][n], fused stats ----
__global__ __launch_bounds__(256) void gemm_kernel(
        const float* __restrict__ W, const short* __restrict__ xfrag,
        float* __restrict__ y, float* __restrict__ csum, float* __restrict__ csumsq) {
    const int lane = threadIdx.x & 63;
    const int wid  = (blockIdx.x << 2) + (threadIdx.x >> 6);   // 0..1999
    const int bj = wid / NMT;
    const int mt = wid - bj * NMT;
    const int b  = bj >> 2;
    const int quad = lane >> 4;
    const int r = lane & 15;

    const float* wp = W + ((size_t)bj * NM + mt * 16 + r) * NM + quad * 8;
    const short* xb = xfrag + (size_t)b * NKT * 2048;   // 2048 shorts per k-tile
    const int loff = lane * 8;

    f32x4 acc0 = {0.f, 0.f, 0.f, 0.f};
    f32x4 acc1 = {0.f, 0.f, 0.f, 0.f};

#define BFRAG(kt, ct, hl) (*(const bf16x8*)(xb + (size_t)(kt) * 2048 + (ct) * 1024 + (hl) * 512 + loff))

    float4 a0c, a1c;
    bf16x8 bh0c, bl0c, bh1c, bl1c;
    // kt = 0 always fully in range
    a0c = *(const float4*)(wp);
    a1c = *(const float4*)(wp + 4);
    bh0c = BFRAG(0, 0, 0); bl0c = BFRAG(0, 0, 1);
    bh1c = BFRAG(0, 1, 0); bl1c = BFRAG(0, 1, 1);

    for (int kt = 0; kt < NKT; ++kt) {
        float4 a0n, a1n;
        bf16x8 bh0n, bl0n, bh1n, bl1n;
        const int ktn = kt + 1;
        if (ktn < NKT) {
            const float4 z4 = make_float4(0.f, 0.f, 0.f, 0.f);
            a0n = z4; a1n = z4;
            // k-tail: kt==62 covers k 1984..2015; quads 2,3 are OOB -> zeros
            if ((ktn < NKT - 1) | (quad < 2)) {
                const float* wpn = wp + ktn * 32;
                a0n = *(const float4*)(wpn);
                a1n = *(const float4*)(wpn + 4);
            }
            bh0n = BFRAG(ktn, 0, 0); bl0n = BFRAG(ktn, 0, 1);
            bh1n = BFRAG(ktn, 1, 0); bl1n = BFRAG(ktn, 1, 1);
        }
        // convert current A tile fp32 -> hi/lo bf16 frags
        bf16x8 ah, al;
        float v[8] = {a0c.x, a0c.y, a0c.z, a0c.w, a1c.x, a1c.y, a1c.z, a1c.w};
#pragma unroll
        for (int j = 0; j < 8; ++j) {
            short h, l;
            bf16_split(v[j], h, l);
            ah[j] = h; al[j] = l;
        }
        acc0 = __builtin_amdgcn_mfma_f32_16x16x32_bf16(ah, bh0c, acc0, 0, 0, 0);
        acc1 = __builtin_amdgcn_mfma_f32_16x16x32_bf16(ah, bh1c, acc1, 0, 0, 0);
        acc0 = __builtin_amdgcn_mfma_f32_16x16x32_bf16(al, bh0c, acc0, 0, 0, 0);
        acc1 = __builtin_amdgcn_mfma_f32_16x16x32_bf16(al, bh1c, acc1, 0, 0, 0);
        acc0 = __builtin_amdgcn_mfma_f32_16x16x32_bf16(ah, bl0c, acc0, 0, 0, 0);
        acc1 = __builtin_amdgcn_mfma_f32_16x16x32_bf16(ah, bl1c, acc1, 0, 0, 0);
        if (ktn < NKT) {
            a0c = a0n; a1c = a1n;
            bh0c = bh0n; bl0c = bl0n; bh1c = bh1n; bl1c = bl1n;
        }
    }

    // ---- fused per-channel stats: sum + sumsq over the 16 rows of this tile ----
    // D layout: col = lane&15 (channel within ctile), row = quad*4 + reg
    float s0 = acc0[0] + acc0[1] + acc0[2] + acc0[3];
    float q0 = acc0[0]*acc0[0] + acc0[1]*acc0[1] + acc0[2]*acc0[2] + acc0[3]*acc0[3];
    float s1 = acc1[0] + acc1[1] + acc1[2] + acc1[3];
    float q1 = acc1[0]*acc1[0] + acc1[1]*acc1[1] + acc1[2]*acc1[2] + acc1[3]*acc1[3];
    s0 += __shfl_xor(s0, 16); s0 += __shfl_xor(s0, 32);
    q0 += __shfl_xor(q0, 16); q0 += __shfl_xor(q0, 32);
    s1 += __shfl_xor(s1, 16); s1 += __shfl_xor(s1, 32);
    q1 += __shfl_xor(q1, 16); q1 += __shfl_xor(q1, 32);
    const int j = bj & 3;
    if (quad == 0) {
        atomicAdd(&csum[j * NC + r], s0);
        atomicAdd(&csumsq[j * NC + r], q0);
        atomicAdd(&csum[j * NC + 16 + r], s1);
        atomicAdd(&csumsq[j * NC + 16 + r], q1);
    }

    // ---- store y tile: y[bj][m][c], c contiguous (32 floats per m) ----
    float* yp = y + ((size_t)bj * NM + mt * 16 + quad * 4) * NC + r;
#pragma unroll
    for (int i = 0; i < 4; ++i) {
        yp[i * NC]      = acc0[i];
        yp[i * NC + 16] = acc1[i];
    }
}

// ---- kernel 3: BN (from stats) + ReLU + 1x1 conv ----
// thread -> (b, m, oq); computes 8 output channels o = oq*8 + u
__global__ __launch_bounds__(256) void conv_kernel(
        const float* __restrict__ y, const float* __restrict__ csum,
        const float* __restrict__ csumsq, const float* __restrict__ gamma,
        const float* __restrict__ beta, const float* __restrict__ conv_w,
        const float* __restrict__ conv_b, float* __restrict__ out) {
    __shared__ float wt[NCH * 32];   // wt[jc*32 + o] = conv_w[o*128 + jc]
    __shared__ float sscale[NCH], sshift[NCH], scb[32];
    const int t = threadIdx.x;
    if (t < NCH) {
        const float inv = 1.f / (NB * NM);
        float mean = csum[t] * inv;
        float var = csumsq[t] * inv - mean * mean;
        var = fmaxf(var, 0.f);
        float rs = rsqrtf(var + BN_EPS);
        float sc = gamma[t] * rs;
        sscale[t] = sc;
        sshift[t] = beta[t] - mean * sc;
    }
    if (t < 32) scb[t] = conv_b[t];
#pragma unroll
    for (int i = t; i < NCH * 32; i += 256)
        wt[i] = conv_w[(i & 31) * NCH + (i >> 5)];
    __syncthreads();

    int g = blockIdx.x * 256 + t;       // 0..31999
    int oq = g & 3;
    int bm = g >> 2;
    int m = bm % NM;
    int b = bm / NM;

    float acc[8];
#pragma unroll
    for (int u = 0; u < 8; ++u) acc[u] = scb[oq * 8 + u];

#pragma unroll
    for (int jj = 0; jj < NJ; ++jj) {
        const float4* y4 = (const float4*)(y + (((size_t)b * NJ + jj) * NM + m) * NC);
#pragma unroll
        for (int q = 0; q < 8; ++q) {
            float4 v = y4[q];
            int jc = jj * NC + q * 4;
            float ya0 = fmaxf(fmaf(v.x, sscale[jc],     sshift[jc]),     0.f);
            float ya1 = fmaxf(fmaf(v.y, sscale[jc + 1], sshift[jc + 1]), 0.f);
            float ya2 = fmaxf(fmaf(v.z, sscale[jc + 2], sshift[jc + 2]), 0.f);
            float ya3 = fmaxf(fmaf(v.w, sscale[jc + 3], sshift[jc + 3]), 0.f);
#pragma unroll
            for (int u = 0; u < 8; ++u) {
                int o = oq * 8 + u;
                acc[u] = fmaf(ya0, wt[(jc)     * 32 + o], acc[u]);
                acc[u] = fmaf(ya1, wt[(jc + 1) * 32 + o], acc[u]);
                acc[u] = fmaf(ya2, wt[(jc + 2) * 32 + o], acc[u]);
                acc[u] = fmaf(ya3, wt[(jc + 3) * 32 + o], acc[u]);
            }
        }
    }
#pragma unroll
    for (int u = 0; u < 8; ++u)
        out[((size_t)b * 32 + oq * 8 + u) * NM + m] = acc[u];
}

extern "C" void kernel_launch(void* const* d_in, const int* in_sizes, int n_in,
                              void* d_out, int out_size, void* d_ws, size_t ws_size,
                              hipStream_t stream) {
    const float* W      = (const float*)d_in[0];
    const float* x      = (const float*)d_in[1];
    const float* gamma  = (const float*)d_in[2];
    const float* beta   = (const float*)d_in[3];
    const float* conv_w = (const float*)d_in[4];
    const float* conv_b = (const float*)d_in[5];
    float* out = (float*)d_out;

    char* ws = (char*)d_ws;
    float* y      = (float*)ws;                  // 16*2000*32 fp32 = 4,096,000 B
    float* csum   = (float*)(ws + 4096000);      // 128 fp32
    float* csumsq = (float*)(ws + 4096512);      // 128 fp32
    short* xfrag  = (short*)(ws + 4097024);      // 4*63*2*2*512 shorts = 1,032,192 B

    prep_kernel<<<126, 256, 0, stream>>>(x, xfrag, csum);
    gemm_kernel<<<500, 256, 0, stream>>>(W, xfrag, y, csum, csumsq);
    conv_kernel<<<125, 256, 0, stream>>>(y, csum, csumsq, gamma, beta, conv_w, conv_b, out);
}